// Round 5
// baseline (1140.403 us; speedup 1.0000x reference)
//
#include <hip/hip_runtime.h>
#include <math.h>

#define SEQ 16
#define HID 1024
#define G4 4096
#define LATENT 2048
#define NBLK 256          // fused grid: 1 block per CU
#define ASTRIDE 16        // arrive-slot stride in u32 (64 B)

__device__ __forceinline__ float sigmoidf_(float x) { return 1.f / (1.f + __expf(-x)); }
__device__ __forceinline__ float tanhf_(float x) { return 1.f - 2.f / (__expf(2.f * x) + 1.f); }
__device__ __forceinline__ float dot4(float4 a, float4 b) {
    return a.x * b.x + a.y * b.y + a.z * b.z + a.w * b.w;
}

// ---------------------------------------------------------------------------
// xg0[t][g] = x[t] . w_ih0[g] + b_ih0[g] + b_hh0[g]   (K = 2048)
// ---------------------------------------------------------------------------
__global__ __launch_bounds__(256) void xg0_gemm(const float* __restrict__ x,
                                                const float* __restrict__ w,
                                                const float* __restrict__ bi,
                                                const float* __restrict__ bh,
                                                float* __restrict__ xg) {
    __shared__ float xs[SEQ][512];  // 32 KB
    const int tid = threadIdx.x, wv = tid >> 6, ln = tid & 63;
    const int g0 = blockIdx.x * 8 + wv * 2;

    float acc0[SEQ], acc1[SEQ];
#pragma unroll
    for (int t = 0; t < SEQ; ++t) { acc0[t] = 0.f; acc1[t] = 0.f; }

    for (int ch = 0; ch < 4; ++ch) {
        __syncthreads();
        const float4* xsrc = (const float4*)x;
#pragma unroll
        for (int i = 0; i < 8; ++i) {
            const int idx = tid + i * 256;
            const int t = idx >> 7;
            const int c = idx & 127;
            ((float4*)xs)[t * 128 + c] = xsrc[t * 512 + ch * 128 + c];
        }
        __syncthreads();
        const float4* w0 = (const float4*)(w + (size_t)g0 * LATENT) + ch * 128;
        const float4* w1 = (const float4*)(w + (size_t)(g0 + 1) * LATENT) + ch * 128;
        const float4 a0 = w0[ln], a1 = w0[ln + 64];
        const float4 b0 = w1[ln], b1 = w1[ln + 64];
#pragma unroll
        for (int t = 0; t < SEQ; ++t) {
            const float4 xa = ((const float4*)xs)[t * 128 + ln];
            const float4 xb = ((const float4*)xs)[t * 128 + ln + 64];
            acc0[t] += dot4(a0, xa) + dot4(a1, xb);
            acc1[t] += dot4(b0, xa) + dot4(b1, xb);
        }
    }
#pragma unroll
    for (int t = 0; t < SEQ; ++t) {
        float v0 = acc0[t], v1 = acc1[t];
#pragma unroll
        for (int off = 32; off; off >>= 1) { v0 += __shfl_xor(v0, off); v1 += __shfl_xor(v1, off); }
        acc0[t] = v0; acc1[t] = v1;
    }
    if (ln < SEQ) {
        xg[ln * G4 + g0]     = acc0[ln] + bi[g0] + bh[g0];
        xg[ln * G4 + g0 + 1] = acc1[ln] + bi[g0 + 1] + bh[g0 + 1];
    }
}

// ---------------------------------------------------------------------------
// Fused two-layer recurrence. 256 blocks x 1024 threads (16 waves), regular
// launch, 1 block/CU co-residency. Block owns hidden units j=4*bid+u,
// wave (u,g) owns gate g of unit u: 12 float4 of weights in VGPRs (48 regs).
// Grid barrier: padded arrive slots, release store by lane0 of wave0 (covers
// all 4 updater lanes' stores via vmcnt drain), all-poll by wave0 with
// wraparound-safe >= compare, acquire threadfence after. Primitives proven
// in R4; 0xAA ws-poison is signed-negative under (int)(v-gen) -> safe.
// ---------------------------------------------------------------------------
__global__ __launch_bounds__(1024, 4) void fused_lstm(
    const float* __restrict__ w_hh0,
    const float* __restrict__ w_ih1,
    const float* __restrict__ w_hh1,
    const float* __restrict__ b_ih1,
    const float* __restrict__ b_hh1,
    const float* __restrict__ xg0,
    float* __restrict__ h1a, float* __restrict__ h1b,
    float* __restrict__ h2a, float* __restrict__ h2b,
    unsigned* __restrict__ arrive,
    float* __restrict__ out) {
    const int bid = blockIdx.x;
    const int tid = threadIdx.x;
    const int wv  = tid >> 6;   // 0..15
    const int ln  = tid & 63;
    const int u   = wv >> 2;    // unit-in-block 0..3
    const int g   = wv & 3;     // gate 0..3
    const int j   = bid * 4 + u;

    __shared__ float4 h1s[256];
    __shared__ float4 h2s[256];
    __shared__ float acts[4][4][2];  // [unit][gate][layer]

    // ---- weights: 12 float4/thread, fully coalesced ----
    float4 wa[4], wb[4], wc[4];
    {
        const float4* p0 = (const float4*)w_hh0 + (size_t)(g * HID + j) * 256;
        const float4* p1 = (const float4*)w_ih1 + (size_t)(g * HID + j) * 256;
        const float4* p2 = (const float4*)w_hh1 + (size_t)(g * HID + j) * 256;
#pragma unroll
        for (int c = 0; c < 4; ++c) {
            wa[c] = p0[ln + 64 * c];
            wb[c] = p1[ln + 64 * c];
            wc[c] = p2[ln + 64 * c];
        }
    }
    // xg0 for all 16 phases of this wave's gate: lane t holds phase t's value
    float xgreg = 0.f;
    if (ln < SEQ) xgreg = xg0[ln * G4 + g * HID + j];
    const float bias1 = b_ih1[g * HID + j] + b_hh1[g * HID + j];

    float c0 = 0.f, c1 = 0.f;  // live in updater lanes (tid 0..3)

    for (int p = 0; p <= SEQ; ++p) {
        const float4* h1r = (const float4*)((p & 1) ? h1a : h1b);
        const float4* h2r = (const float4*)((p & 1) ? h2a : h2b);
        float* h1w = (p & 1) ? h1b : h1a;
        float* h2w = (p & 1) ? h2b : h2a;

        // ---- stage previous h into LDS ----
        if (p >= 1 && tid < 256)                h1s[tid] = h1r[tid];
        if (p >= 2 && tid >= 256 && tid < 512)  h2s[tid - 256] = h2r[tid - 256];
        __syncthreads();

        // ---- per-wave gate dots ----
        float d0 = 0.f, d1 = 0.f, d2 = 0.f;
        if (p >= 1) {
#pragma unroll
            for (int c = 0; c < 4; ++c) {
                const float4 h = h1s[ln + 64 * c];
                d0 += dot4(wa[c], h);
                d1 += dot4(wb[c], h);
            }
        }
        if (p >= 2) {
#pragma unroll
            for (int c = 0; c < 4; ++c) d2 += dot4(wc[c], h2s[ln + 64 * c]);
        }
#pragma unroll
        for (int off = 32; off; off >>= 1) {
            d0 += __shfl_xor(d0, off);
            d1 += __shfl_xor(d1, off);
            d2 += __shfl_xor(d2, off);
        }
        const float xp = __shfl(xgreg, p & 15);  // all lanes participate
        if (ln == 0) {
            if (p < SEQ)
                acts[u][g][0] = (g == 2) ? tanhf_(xp + d0) : sigmoidf_(xp + d0);
            if (p >= 1)
                acts[u][g][1] = (g == 2) ? tanhf_(d1 + bias1 + d2)
                                         : sigmoidf_(d1 + bias1 + d2);
        }
        __syncthreads();

        // ---- cell update: threads 0..3 (wave 0), unit = tid ----
        if (tid < 4) {
            const int jj = bid * 4 + tid;
            if (p < SEQ) {
                c0 = acts[tid][1][0] * c0 + acts[tid][0][0] * acts[tid][2][0];
                h1w[jj] = acts[tid][3][0] * tanhf_(c0);
            }
            if (p >= 1) {
                c1 = acts[tid][1][1] * c1 + acts[tid][0][1] * acts[tid][2][1];
                const float h2v = acts[tid][3][1] * tanhf_(c1);
                h2w[jj] = h2v;
                out[HID + (p - 1) * HID + jj] = h2v;
                if (p == SEQ) out[jj] = h2v;
            }
        }

        // ---- grid barrier (not after the last phase) ----
        if (p < SEQ) {
            const unsigned gen = (unsigned)(p + 1);
            if (tid == 0)
                __hip_atomic_store(&arrive[bid * ASTRIDE], gen, __ATOMIC_RELEASE,
                                   __HIP_MEMORY_SCOPE_AGENT);
            if (wv == 0) {
#pragma unroll
                for (int k = 0; k < 4; ++k) {
                    const unsigned* slot = &arrive[(ln * 4 + k) * ASTRIDE];
                    while ((int)(__hip_atomic_load(slot, __ATOMIC_RELAXED,
                                                   __HIP_MEMORY_SCOPE_AGENT) - gen) < 0)
                        __builtin_amdgcn_s_sleep(1);
                }
            }
            __syncthreads();
            __threadfence();  // acquire: L1/L2 invalidate so h reads are fresh
        }
    }
}

extern "C" void kernel_launch(void* const* d_in, const int* in_sizes, int n_in,
                              void* d_out, int out_size, void* d_ws, size_t ws_size,
                              hipStream_t stream) {
    const float* x     = (const float*)d_in[0];
    const float* w_ih0 = (const float*)d_in[1];
    const float* w_hh0 = (const float*)d_in[2];
    const float* b_ih0 = (const float*)d_in[3];
    const float* b_hh0 = (const float*)d_in[4];
    const float* w_ih1 = (const float*)d_in[5];
    const float* w_hh1 = (const float*)d_in[6];
    const float* b_ih1 = (const float*)d_in[7];
    const float* b_hh1 = (const float*)d_in[8];

    float* xg  = (float*)d_ws;            // 65536 floats
    float* h1a = xg + SEQ * G4;           // 1024
    float* h1b = h1a + HID;
    float* h2a = h1b + HID;
    float* h2b = h2a + HID;
    unsigned* arrive = (unsigned*)(h2b + HID);  // 256*16 u32 = 16 KB
    float* out = (float*)d_out;

    xg0_gemm<<<512, 256, 0, stream>>>(x, w_ih0, b_ih0, b_hh0, xg);
    fused_lstm<<<NBLK, 1024, 0, stream>>>(w_hh0, w_ih1, w_hh1, b_ih1, b_hh1,
                                          xg, h1a, h1b, h2a, h2b, arrive, out);
}

// Round 6
// 205.592 us; speedup vs baseline: 5.5469x; 5.5469x over previous
//
#include <hip/hip_runtime.h>
#include <math.h>

#define SEQ 16
#define HID 1024
#define G4 4096
#define LATENT 2048
#define NBLK 256          // fused grid: 1 block per CU
#define ASTRIDE 16        // arrive-slot stride in u32 (64 B)

typedef float f4 __attribute__((ext_vector_type(4)));

__device__ __forceinline__ float sigmoidf_(float x) { return 1.f / (1.f + __expf(-x)); }
__device__ __forceinline__ float tanhf_(float x) { return 1.f - 2.f / (__expf(2.f * x) + 1.f); }
__device__ __forceinline__ float dot4(float4 a, float4 b) {
    return a.x * b.x + a.y * b.y + a.z * b.z + a.w * b.w;
}
__device__ __forceinline__ float dot4e(f4 a, f4 b) {
    return a.x * b.x + a.y * b.y + a.z * b.z + a.w * b.w;
}

// ---------------------------------------------------------------------------
// xg0[t][g] = x[t] . w_ih0[g] + b_ih0[g] + b_hh0[g]   (K = 2048)  [R4-proven]
// ---------------------------------------------------------------------------
__global__ __launch_bounds__(256) void xg0_gemm(const float* __restrict__ x,
                                                const float* __restrict__ w,
                                                const float* __restrict__ bi,
                                                const float* __restrict__ bh,
                                                float* __restrict__ xg) {
    __shared__ float xs[SEQ][512];  // 32 KB
    const int tid = threadIdx.x, wv = tid >> 6, ln = tid & 63;
    const int g0 = blockIdx.x * 8 + wv * 2;

    float acc0[SEQ], acc1[SEQ];
#pragma unroll
    for (int t = 0; t < SEQ; ++t) { acc0[t] = 0.f; acc1[t] = 0.f; }

    for (int ch = 0; ch < 4; ++ch) {
        __syncthreads();
        const float4* xsrc = (const float4*)x;
#pragma unroll
        for (int i = 0; i < 8; ++i) {
            const int idx = tid + i * 256;
            const int t = idx >> 7;
            const int c = idx & 127;
            ((float4*)xs)[t * 128 + c] = xsrc[t * 512 + ch * 128 + c];
        }
        __syncthreads();
        const float4* w0 = (const float4*)(w + (size_t)g0 * LATENT) + ch * 128;
        const float4* w1 = (const float4*)(w + (size_t)(g0 + 1) * LATENT) + ch * 128;
        const float4 a0 = w0[ln], a1 = w0[ln + 64];
        const float4 b0 = w1[ln], b1 = w1[ln + 64];
#pragma unroll
        for (int t = 0; t < SEQ; ++t) {
            const float4 xa = ((const float4*)xs)[t * 128 + ln];
            const float4 xb = ((const float4*)xs)[t * 128 + ln + 64];
            acc0[t] += dot4(a0, xa) + dot4(a1, xb);
            acc1[t] += dot4(b0, xa) + dot4(b1, xb);
        }
    }
#pragma unroll
    for (int t = 0; t < SEQ; ++t) {
        float v0 = acc0[t], v1 = acc1[t];
#pragma unroll
        for (int off = 32; off; off >>= 1) { v0 += __shfl_xor(v0, off); v1 += __shfl_xor(v1, off); }
        acc0[t] = v0; acc1[t] = v1;
    }
    if (ln < SEQ) {
        xg[ln * G4 + g0]     = acc0[ln] + bi[g0] + bh[g0];
        xg[ln * G4 + g0 + 1] = acc1[ln] + bi[g0 + 1] + bh[g0 + 1];
    }
}

// ---------------------------------------------------------------------------
// Fused two-layer recurrence. 256 blocks x 1024 threads, wave (u,g) owns gate
// g of hidden unit j=4*bid+u; 12 f4 of weights asm-pinned in VGPRs.
// NO release/acquire/fence in the loop: all cross-block traffic (h values,
// barrier flags) uses RELAXED AGENT-scope atomics (coherent-point access, no
// L2 writeback/invalidate). Producer orders h-stores before flag-store with a
// raw s_waitcnt vmcnt(0); consumers' data reads are themselves coherent
// atomics, so in-order wave issue after a successful poll suffices.
// ---------------------------------------------------------------------------
__global__ __launch_bounds__(1024, 4) void fused_lstm(
    const float* __restrict__ w_hh0,
    const float* __restrict__ w_ih1,
    const float* __restrict__ w_hh1,
    const float* __restrict__ b_ih1,
    const float* __restrict__ b_hh1,
    const float* __restrict__ xg0,
    float* __restrict__ h1a, float* __restrict__ h1b,
    float* __restrict__ h2a, float* __restrict__ h2b,
    unsigned* __restrict__ arrive,
    float* __restrict__ out) {
    const int bid = blockIdx.x;
    const int tid = threadIdx.x;
    const int wv  = tid >> 6;   // 0..15
    const int ln  = tid & 63;
    const int u   = wv >> 2;    // unit-in-block 0..3
    const int g   = wv & 3;     // gate 0..3
    const int j   = bid * 4 + u;

    __shared__ float h1sf[HID >> 0 == 1024 ? 1024 : 1024];
    __shared__ float h2sf[1024];
    __shared__ float acts[4][4][2];  // [unit][gate][layer]

    // ---- weights: 12 f4/thread, asm-pinned so they stay in VGPRs ----
    f4 wa[4], wb[4], wc[4];
    {
        const f4* p0 = (const f4*)(w_hh0 + (size_t)(g * HID + j) * HID);
        const f4* p1 = (const f4*)(w_ih1 + (size_t)(g * HID + j) * HID);
        const f4* p2 = (const f4*)(w_hh1 + (size_t)(g * HID + j) * HID);
#pragma unroll
        for (int c = 0; c < 4; ++c) {
            wa[c] = p0[ln + 64 * c];
            wb[c] = p1[ln + 64 * c];
            wc[c] = p2[ln + 64 * c];
        }
    }
#pragma unroll
    for (int c = 0; c < 4; ++c) {
        asm volatile("" : "+v"(wa[c]));
        asm volatile("" : "+v"(wb[c]));
        asm volatile("" : "+v"(wc[c]));
    }
    float xgreg = 0.f;
    if (ln < SEQ) xgreg = xg0[ln * G4 + g * HID + j];
    float bias1 = b_ih1[g * HID + j] + b_hh1[g * HID + j];
    asm volatile("" : "+v"(xgreg), "+v"(bias1));

    float c0 = 0.f, c1 = 0.f;  // live in lanes tid 0..3

    for (int p = 0; p <= SEQ; ++p) {
        const float* h1r = (p & 1) ? h1a : h1b;
        const float* h2r = (p & 1) ? h2a : h2b;
        float* h1w = (p & 1) ? h1b : h1a;
        float* h2w = (p & 1) ? h2b : h2a;

        // ---- stage previous h into LDS (coherent relaxed atomic loads) ----
        if (p >= 1)
            h1sf[tid] = __hip_atomic_load(&h1r[tid], __ATOMIC_RELAXED,
                                          __HIP_MEMORY_SCOPE_AGENT);
        if (p >= 2)
            h2sf[tid] = __hip_atomic_load(&h2r[tid], __ATOMIC_RELAXED,
                                          __HIP_MEMORY_SCOPE_AGENT);
        __syncthreads();

        // ---- per-wave gate dots ----
        float d0 = 0.f, d1 = 0.f, d2 = 0.f;
        if (p >= 1) {
#pragma unroll
            for (int c = 0; c < 4; ++c) {
                const f4 h = ((const f4*)h1sf)[ln + 64 * c];
                d0 += dot4e(wa[c], h);
                d1 += dot4e(wb[c], h);
            }
        }
        if (p >= 2) {
#pragma unroll
            for (int c = 0; c < 4; ++c)
                d2 += dot4e(wc[c], ((const f4*)h2sf)[ln + 64 * c]);
        }
#pragma unroll
        for (int off = 32; off; off >>= 1) {
            d0 += __shfl_xor(d0, off);
            d1 += __shfl_xor(d1, off);
            d2 += __shfl_xor(d2, off);
        }
        const float xp = __shfl(xgreg, p & 15);
        if (ln == 0) {
            if (p < SEQ)
                acts[u][g][0] = (g == 2) ? tanhf_(xp + d0) : sigmoidf_(xp + d0);
            if (p >= 1)
                acts[u][g][1] = (g == 2) ? tanhf_(d1 + bias1 + d2)
                                         : sigmoidf_(d1 + bias1 + d2);
        }
        __syncthreads();

        // ---- cell update: threads 0..3, unit = tid ----
        if (tid < 4) {
            const int jj = bid * 4 + tid;
            if (p < SEQ) {
                c0 = acts[tid][1][0] * c0 + acts[tid][0][0] * acts[tid][2][0];
                const float h1v = acts[tid][3][0] * tanhf_(c0);
                __hip_atomic_store(&h1w[jj], h1v, __ATOMIC_RELAXED,
                                   __HIP_MEMORY_SCOPE_AGENT);
            }
            if (p >= 1) {
                c1 = acts[tid][1][1] * c1 + acts[tid][0][1] * acts[tid][2][1];
                const float h2v = acts[tid][3][1] * tanhf_(c1);
                __hip_atomic_store(&h2w[jj], h2v, __ATOMIC_RELAXED,
                                   __HIP_MEMORY_SCOPE_AGENT);
                out[HID + (p - 1) * HID + jj] = h2v;
                if (p == SEQ) out[jj] = h2v;
            }
        }

        // ---- grid barrier (no cache-maintenance ops) ----
        if (p < SEQ) {
            const unsigned gen = (unsigned)(p + 1);
            // hardware release: drain this wave's h-stores before flag store
            asm volatile("s_waitcnt vmcnt(0)" ::: "memory");
            if (tid == 0)
                __hip_atomic_store(&arrive[bid * ASTRIDE], gen, __ATOMIC_RELAXED,
                                   __HIP_MEMORY_SCOPE_AGENT);
            if (wv == 0) {
#pragma unroll
                for (int k = 0; k < 4; ++k) {
                    const unsigned* slot = &arrive[(ln * 4 + k) * ASTRIDE];
                    while ((int)(__hip_atomic_load(slot, __ATOMIC_RELAXED,
                                                   __HIP_MEMORY_SCOPE_AGENT) - gen) < 0)
                        __builtin_amdgcn_s_sleep(1);
                }
            }
            __syncthreads();
        }
    }
}

extern "C" void kernel_launch(void* const* d_in, const int* in_sizes, int n_in,
                              void* d_out, int out_size, void* d_ws, size_t ws_size,
                              hipStream_t stream) {
    const float* x     = (const float*)d_in[0];
    const float* w_ih0 = (const float*)d_in[1];
    const float* w_hh0 = (const float*)d_in[2];
    const float* b_ih0 = (const float*)d_in[3];
    const float* b_hh0 = (const float*)d_in[4];
    const float* w_ih1 = (const float*)d_in[5];
    const float* w_hh1 = (const float*)d_in[6];
    const float* b_ih1 = (const float*)d_in[7];
    const float* b_hh1 = (const float*)d_in[8];

    float* xg  = (float*)d_ws;            // 65536 floats
    float* h1a = xg + SEQ * G4;           // 1024
    float* h1b = h1a + HID;
    float* h2a = h1b + HID;
    float* h2b = h2a + HID;
    unsigned* arrive = (unsigned*)(h2b + HID);  // 256*16 u32 = 16 KB
    float* out = (float*)d_out;

    xg0_gemm<<<512, 256, 0, stream>>>(x, w_ih0, b_ih0, b_hh0, xg);
    fused_lstm<<<NBLK, 1024, 0, stream>>>(w_hh0, w_ih1, w_hh1, b_ih1, b_hh1,
                                          xg, h1a, h1b, h2a, h2b, arrive, out);
}

// Round 7
// 192.927 us; speedup vs baseline: 5.9111x; 1.0657x over previous
//
#include <hip/hip_runtime.h>
#include <math.h>

#define SEQ 16
#define HID 1024
#define G4 4096
#define LATENT 2048
#define NBLK 256          // 1 block per CU
#define ASTRIDE 16        // arrive-slot stride in u32 (64 B)

typedef float f4 __attribute__((ext_vector_type(4)));

__device__ __forceinline__ float sigmoidf_(float x) { return 1.f / (1.f + __expf(-x)); }
__device__ __forceinline__ float tanhf_(float x) { return 1.f - 2.f / (__expf(2.f * x) + 1.f); }
__device__ __forceinline__ float dot4e(f4 a, f4 b) {
    return a.x * b.x + a.y * b.y + a.z * b.z + a.w * b.w;
}

// ---------------------------------------------------------------------------
// Single fused kernel: xg0 prologue + two-layer recurrence.
// 256 blocks x 1024 threads. Wave (u,g) owns gate g of hidden unit j=4*bid+u,
// i.e. row r = g*1024+j of all three recurrent weight matrices AND of w_ih0.
// Prologue: stage x in LDS (4 chunks x 32KB), compute xg0[t][r] for t=0..15,
//           butterfly-reduce -> lane t holds xgreg (+b_ih0+b_hh0).
// Phases:   identical to R6 (relaxed agent atomics for h exchange + barrier,
//           raw vmcnt(0) as release, no cache-maintenance ops in loop).
// Weights:  12 NAMED f4 (no arrays), asm-pinned -> must stay VGPR-resident.
// ---------------------------------------------------------------------------
__global__ __launch_bounds__(1024, 4) void fused_all(
    const float* __restrict__ x,
    const float* __restrict__ w_ih0,
    const float* __restrict__ w_hh0,
    const float* __restrict__ b_ih0,
    const float* __restrict__ b_hh0,
    const float* __restrict__ w_ih1,
    const float* __restrict__ w_hh1,
    const float* __restrict__ b_ih1,
    const float* __restrict__ b_hh1,
    float* __restrict__ h1a, float* __restrict__ h1b,
    float* __restrict__ h2a, float* __restrict__ h2b,
    unsigned* __restrict__ arrive,
    float* __restrict__ out) {
    const int bid = blockIdx.x;
    const int tid = threadIdx.x;
    const int wv  = tid >> 6;   // 0..15
    const int ln  = tid & 63;
    const int u   = wv >> 2;    // unit-in-block 0..3
    const int g   = wv & 3;     // gate 0..3
    const int j   = bid * 4 + u;
    const int r   = g * HID + j;   // weight row, 0..4095

    __shared__ f4    xs4[SEQ * 128];   // 32 KB: one 512-float K-chunk per row
    __shared__ float h1sf[HID];        // 4 KB
    __shared__ float h2sf[HID];        // 4 KB
    __shared__ float acts[4][4][2];    // [unit][gate][layer]

    // ---------------- prologue: xg0 for this wave's row r ----------------
    float acc[SEQ];
#pragma unroll
    for (int t = 0; t < SEQ; ++t) acc[t] = 0.f;

    const f4* xsrc = (const f4*)x;   // [16][512] f4
    for (int ch = 0; ch < 4; ++ch) {
        __syncthreads();
        {   // stage 2048 f4 (32 KB) with 1024 threads: 2 each
            const int i0 = tid, i1 = tid + 1024;
            xs4[i0] = xsrc[(i0 >> 7) * 512 + ch * 128 + (i0 & 127)];
            xs4[i1] = xsrc[(i1 >> 7) * 512 + ch * 128 + (i1 & 127)];
        }
        __syncthreads();
        const f4* wrow = (const f4*)(w_ih0 + (size_t)r * LATENT) + ch * 128;
        const f4 a0 = wrow[ln], a1 = wrow[ln + 64];
#pragma unroll
        for (int t = 0; t < SEQ; ++t)
            acc[t] += dot4e(a0, xs4[t * 128 + ln]) + dot4e(a1, xs4[t * 128 + ln + 64]);
    }
    float xgreg = 0.f;
    {
        const float bsum = b_ih0[r] + b_hh0[r];
#pragma unroll
        for (int t = 0; t < SEQ; ++t) {
            float v = acc[t];
#pragma unroll
            for (int off = 32; off; off >>= 1) v += __shfl_xor(v, off);
            if (ln == t) xgreg = v + bsum;
        }
    }

    // ---------------- recurrent weights: 12 named f4, pinned ----------------
    const f4* p0 = (const f4*)(w_hh0 + (size_t)r * HID);
    const f4* p1 = (const f4*)(w_ih1 + (size_t)r * HID);
    const f4* p2 = (const f4*)(w_hh1 + (size_t)r * HID);
    f4 wa0 = p0[ln], wa1 = p0[ln + 64], wa2 = p0[ln + 128], wa3 = p0[ln + 192];
    f4 wb0 = p1[ln], wb1 = p1[ln + 64], wb2 = p1[ln + 128], wb3 = p1[ln + 192];
    f4 wc0 = p2[ln], wc1 = p2[ln + 64], wc2 = p2[ln + 128], wc3 = p2[ln + 192];
    asm volatile("" : "+v"(wa0), "+v"(wa1), "+v"(wa2), "+v"(wa3));
    asm volatile("" : "+v"(wb0), "+v"(wb1), "+v"(wb2), "+v"(wb3));
    asm volatile("" : "+v"(wc0), "+v"(wc1), "+v"(wc2), "+v"(wc3));

    float bias1 = b_ih1[r] + b_hh1[r];
    asm volatile("" : "+v"(xgreg), "+v"(bias1));

    float c0 = 0.f, c1 = 0.f;  // live in lanes tid 0..3

    // ---------------- phases ----------------
    for (int p = 0; p <= SEQ; ++p) {
        const float* h1r = (p & 1) ? h1a : h1b;
        const float* h2r = (p & 1) ? h2a : h2b;
        float* h1w = (p & 1) ? h1b : h1a;
        float* h2w = (p & 1) ? h2b : h2a;

        // ---- stage previous h into LDS (coherent relaxed atomic loads) ----
        if (p >= 1)
            h1sf[tid] = __hip_atomic_load(&h1r[tid], __ATOMIC_RELAXED,
                                          __HIP_MEMORY_SCOPE_AGENT);
        if (p >= 2)
            h2sf[tid] = __hip_atomic_load(&h2r[tid], __ATOMIC_RELAXED,
                                          __HIP_MEMORY_SCOPE_AGENT);
        __syncthreads();

        // ---- per-wave gate dots ----
        float d0 = 0.f, d1 = 0.f, d2 = 0.f;
        if (p >= 1) {
            const f4* h4 = (const f4*)h1sf;
            const f4 h0 = h4[ln], h1v = h4[ln + 64], h2v = h4[ln + 128], h3v = h4[ln + 192];
            d0 = dot4e(wa0, h0) + dot4e(wa1, h1v) + dot4e(wa2, h2v) + dot4e(wa3, h3v);
            d1 = dot4e(wb0, h0) + dot4e(wb1, h1v) + dot4e(wb2, h2v) + dot4e(wb3, h3v);
        }
        if (p >= 2) {
            const f4* h4 = (const f4*)h2sf;
            const f4 h0 = h4[ln], h1v = h4[ln + 64], h2v = h4[ln + 128], h3v = h4[ln + 192];
            d2 = dot4e(wc0, h0) + dot4e(wc1, h1v) + dot4e(wc2, h2v) + dot4e(wc3, h3v);
        }
#pragma unroll
        for (int off = 32; off; off >>= 1) {
            d0 += __shfl_xor(d0, off);
            d1 += __shfl_xor(d1, off);
            d2 += __shfl_xor(d2, off);
        }
        const float xp = __shfl(xgreg, p & 15);
        if (ln == 0) {
            if (p < SEQ)
                acts[u][g][0] = (g == 2) ? tanhf_(xp + d0) : sigmoidf_(xp + d0);
            if (p >= 1)
                acts[u][g][1] = (g == 2) ? tanhf_(d1 + bias1 + d2)
                                         : sigmoidf_(d1 + bias1 + d2);
        }
        __syncthreads();

        // ---- cell update: threads 0..3 (all in wave 0), unit = tid ----
        if (tid < 4) {
            const int jj = bid * 4 + tid;
            if (p < SEQ) {
                c0 = acts[tid][1][0] * c0 + acts[tid][0][0] * acts[tid][2][0];
                const float h1x = acts[tid][3][0] * tanhf_(c0);
                __hip_atomic_store(&h1w[jj], h1x, __ATOMIC_RELAXED,
                                   __HIP_MEMORY_SCOPE_AGENT);
            }
            if (p >= 1) {
                c1 = acts[tid][1][1] * c1 + acts[tid][0][1] * acts[tid][2][1];
                const float h2x = acts[tid][3][1] * tanhf_(c1);
                __hip_atomic_store(&h2w[jj], h2x, __ATOMIC_RELAXED,
                                   __HIP_MEMORY_SCOPE_AGENT);
                out[HID + (p - 1) * HID + jj] = h2x;
                if (p == SEQ) out[jj] = h2x;
            }
        }

        // ---- grid barrier (no cache-maintenance ops) ----
        if (p < SEQ) {
            const unsigned gen = (unsigned)(p + 1);
            // hardware release: drain wave 0's h-stores before the flag store
            asm volatile("s_waitcnt vmcnt(0)" ::: "memory");
            if (tid == 0)
                __hip_atomic_store(&arrive[bid * ASTRIDE], gen, __ATOMIC_RELAXED,
                                   __HIP_MEMORY_SCOPE_AGENT);
            if (wv == 0) {
#pragma unroll
                for (int k = 0; k < 4; ++k) {
                    const unsigned* slot = &arrive[(ln * 4 + k) * ASTRIDE];
                    while ((int)(__hip_atomic_load(slot, __ATOMIC_RELAXED,
                                                   __HIP_MEMORY_SCOPE_AGENT) - gen) < 0)
                        __builtin_amdgcn_s_sleep(1);
                }
            }
            __syncthreads();
        }
    }
}

extern "C" void kernel_launch(void* const* d_in, const int* in_sizes, int n_in,
                              void* d_out, int out_size, void* d_ws, size_t ws_size,
                              hipStream_t stream) {
    const float* x     = (const float*)d_in[0];
    const float* w_ih0 = (const float*)d_in[1];
    const float* w_hh0 = (const float*)d_in[2];
    const float* b_ih0 = (const float*)d_in[3];
    const float* b_hh0 = (const float*)d_in[4];
    const float* w_ih1 = (const float*)d_in[5];
    const float* w_hh1 = (const float*)d_in[6];
    const float* b_ih1 = (const float*)d_in[7];
    const float* b_hh1 = (const float*)d_in[8];

    float* h1a = (float*)d_ws;
    float* h1b = h1a + HID;
    float* h2a = h1b + HID;
    float* h2b = h2a + HID;
    unsigned* arrive = (unsigned*)(h2b + HID);  // 256*16 u32 = 16 KB
    float* out = (float*)d_out;

    fused_all<<<NBLK, 1024, 0, stream>>>(x, w_ih0, w_hh0, b_ih0, b_hh0,
                                         w_ih1, w_hh1, b_ih1, b_hh1,
                                         h1a, h1b, h2a, h2b, arrive, out);
}